// Round 1
// 4507.080 us; speedup vs baseline: 1.1805x; 1.1805x over previous
//
#include <hip/hip_runtime.h>
#include <math.h>

#define D_MODEL 768
#define D_INNER 1536
#define D_STATE 16
#define DT_RANK 48
#define NLAYERS 24
#define BATCH 2
#define SEQ 256
#define M_ROWS (BATCH*SEQ)   // 512
#define DBC_COLS (DT_RANK + 2*D_STATE)  // 80

typedef __bf16 bf16x8 __attribute__((ext_vector_type(8)));
typedef float f32x4 __attribute__((ext_vector_type(4)));

__device__ __forceinline__ float siluf(float x) {
    return x / (1.0f + __expf(-x));
}

// ---------------- embedding gather: h[m,:] = embed[ids[m],:] ----------------
__global__ __launch_bounds__(256) void gather_kernel(const int* __restrict__ ids,
        const float* __restrict__ embed, float* __restrict__ h) {
    int m = blockIdx.x;
    long id = ids[m];
    const float* src = embed + id * D_MODEL;
    float* dst = h + m * D_MODEL;
    for (int k = threadIdx.x; k < D_MODEL; k += 256) dst[k] = src[k];
}

// ---------------- RMS norm ---------------------------------------------------
__global__ __launch_bounds__(256) void rmsnorm_kernel(const float* __restrict__ h,
        const float* __restrict__ w, float* __restrict__ x) {
    int m = blockIdx.x;
    const float* row = h + m * D_MODEL;
    float v[3];
    float ss = 0.f;
    #pragma unroll
    for (int i = 0; i < 3; ++i) {
        v[i] = row[threadIdx.x + i * 256];
        ss += v[i] * v[i];
    }
    #pragma unroll
    for (int off = 32; off > 0; off >>= 1) ss += __shfl_down(ss, off);
    __shared__ float wsum[4];
    int lane = threadIdx.x & 63, wid = threadIdx.x >> 6;
    if (lane == 0) wsum[wid] = ss;
    __syncthreads();
    float tot = wsum[0] + wsum[1] + wsum[2] + wsum[3];
    float inv = rsqrtf(tot / (float)D_MODEL + 1e-5f);
    float* xrow = x + m * D_MODEL;
    #pragma unroll
    for (int i = 0; i < 3; ++i) {
        int k = threadIdx.x + i * 256;
        xrow[k] = v[i] * inv * w[k];
    }
}

// ---------------- NT GEMM via MFMA, fp32 through bf16x2 split ----------------
// C[M,N] = A[M,K(lda)] * B[N,K(ldb)]^T
// Each fp32 operand split a = a_hi + a_lo (bf16 each); all 4 product terms
// accumulated -> ~fp32 accuracy at the bf16 MFMA rate.
// Tile 64x64, K-step 32. 4 waves, each computes a 32x32 quadrant (2x2 frags
// of 16x16x32). Split-K via blockIdx.z (partials laid out [z][M][N]).
// epi: 0 = plain store, 1 = softplus(acc + bias[n]) store.
__global__ __launch_bounds__(256) void gemm_nt_mfma(const float* __restrict__ A,
        const float* __restrict__ B, float* __restrict__ C,
        int M, int N, int K, int lda, int ldb,
        const float* __restrict__ bias, int epi, int kchunk) {
    __shared__ __align__(16) __bf16 Ah[64][32];
    __shared__ __align__(16) __bf16 Al[64][32];
    __shared__ __align__(16) __bf16 Bh[64][32];
    __shared__ __align__(16) __bf16 Bl[64][32];
    const int t = threadIdx.x;
    const int m0 = blockIdx.y * 64, n0 = blockIdx.x * 64;
    const int kbeg = blockIdx.z * kchunk;
    const int kend = min(K, kbeg + kchunk);
    // staging role: thread t loads 8 consecutive k of one row
    const int srow = t >> 2;           // 0..63
    const int skof = (t & 3) * 8;      // 0,8,16,24
    // compute role
    const int lane = t & 63;
    const int w = t >> 6;
    const int wm = (w >> 1) * 32, wn = (w & 1) * 32;
    const int lr = lane & 15, lg = lane >> 4;
    f32x4 acc[2][2] = {};
    const float* Ap0 = A + (size_t)(m0 + srow) * lda + skof;
    const bool nv = (n0 + srow) < N;
    const float* Bp0 = nv ? (B + (size_t)(n0 + srow) * ldb + skof) : A;
    for (int k0 = kbeg; k0 < kend; k0 += 32) {
        // ---- stage A tile (convert f32 -> bf16 hi/lo) ----
        float va[8];
        if (k0 + skof + 8 <= kend) {
            float4 p = *(const float4*)(Ap0 + k0);
            float4 q = *(const float4*)(Ap0 + k0 + 4);
            va[0] = p.x; va[1] = p.y; va[2] = p.z; va[3] = p.w;
            va[4] = q.x; va[5] = q.y; va[6] = q.z; va[7] = q.w;
        } else {
            #pragma unroll
            for (int j = 0; j < 8; ++j)
                va[j] = (k0 + skof + j < kend) ? Ap0[k0 + j] : 0.f;
        }
        {
            bf16x8 hv, lv;
            #pragma unroll
            for (int j = 0; j < 8; ++j) {
                __bf16 hb = (__bf16)va[j];
                hv[j] = hb;
                lv[j] = (__bf16)(va[j] - (float)hb);
            }
            *reinterpret_cast<bf16x8*>(&Ah[srow][skof]) = hv;
            *reinterpret_cast<bf16x8*>(&Al[srow][skof]) = lv;
        }
        // ---- stage B tile ----
        float vb[8];
        if (nv) {
            if (k0 + skof + 8 <= kend) {
                float4 p = *(const float4*)(Bp0 + k0);
                float4 q = *(const float4*)(Bp0 + k0 + 4);
                vb[0] = p.x; vb[1] = p.y; vb[2] = p.z; vb[3] = p.w;
                vb[4] = q.x; vb[5] = q.y; vb[6] = q.z; vb[7] = q.w;
            } else {
                #pragma unroll
                for (int j = 0; j < 8; ++j)
                    vb[j] = (k0 + skof + j < kend) ? Bp0[k0 + j] : 0.f;
            }
        } else {
            #pragma unroll
            for (int j = 0; j < 8; ++j) vb[j] = 0.f;
        }
        {
            bf16x8 hv, lv;
            #pragma unroll
            for (int j = 0; j < 8; ++j) {
                __bf16 hb = (__bf16)vb[j];
                hv[j] = hb;
                lv[j] = (__bf16)(vb[j] - (float)hb);
            }
            *reinterpret_cast<bf16x8*>(&Bh[srow][skof]) = hv;
            *reinterpret_cast<bf16x8*>(&Bl[srow][skof]) = lv;
        }
        __syncthreads();
        // ---- MFMA: 2x2 fragments x 4 split terms ----
        bf16x8 ah[2], al[2], bh[2], bl[2];
        #pragma unroll
        for (int mi = 0; mi < 2; ++mi) {
            ah[mi] = *reinterpret_cast<const bf16x8*>(&Ah[wm + mi * 16 + lr][lg * 8]);
            al[mi] = *reinterpret_cast<const bf16x8*>(&Al[wm + mi * 16 + lr][lg * 8]);
        }
        #pragma unroll
        for (int ni = 0; ni < 2; ++ni) {
            bh[ni] = *reinterpret_cast<const bf16x8*>(&Bh[wn + ni * 16 + lr][lg * 8]);
            bl[ni] = *reinterpret_cast<const bf16x8*>(&Bl[wn + ni * 16 + lr][lg * 8]);
        }
        #pragma unroll
        for (int mi = 0; mi < 2; ++mi) {
            #pragma unroll
            for (int ni = 0; ni < 2; ++ni) {
                acc[mi][ni] = __builtin_amdgcn_mfma_f32_16x16x32_bf16(ah[mi], bh[ni], acc[mi][ni], 0, 0, 0);
                acc[mi][ni] = __builtin_amdgcn_mfma_f32_16x16x32_bf16(al[mi], bh[ni], acc[mi][ni], 0, 0, 0);
                acc[mi][ni] = __builtin_amdgcn_mfma_f32_16x16x32_bf16(ah[mi], bl[ni], acc[mi][ni], 0, 0, 0);
                acc[mi][ni] = __builtin_amdgcn_mfma_f32_16x16x32_bf16(al[mi], bl[ni], acc[mi][ni], 0, 0, 0);
            }
        }
        __syncthreads();
    }
    // ---- epilogue: C/D layout col=lane&15, row=(lane>>4)*4+reg ----
    float* Cz = C + (gridDim.z > 1 ? (size_t)blockIdx.z * M * N : 0);
    #pragma unroll
    for (int mi = 0; mi < 2; ++mi) {
        #pragma unroll
        for (int ni = 0; ni < 2; ++ni) {
            int n = n0 + wn + ni * 16 + lr;
            if (n < N) {
                #pragma unroll
                for (int r = 0; r < 4; ++r) {
                    int m = m0 + wm + mi * 16 + lg * 4 + r;
                    float vv = acc[mi][ni][r];
                    if (epi == 1) {
                        vv += bias[n];
                        vv = vv > 20.f ? vv : log1pf(expf(vv));
                    }
                    Cz[(size_t)m * N + n] = vv;
                }
            }
        }
    }
}

// ---------------- reduce 4 split-K partials ---------------------------------
__global__ __launch_bounds__(256) void reduce_splitk(const float* __restrict__ P,
        float* __restrict__ C, int MN, int accum) {
    int i = blockIdx.x * 256 + threadIdx.x;
    if (i < MN) {
        float v = P[i] + P[MN + i] + P[2 * MN + i] + P[3 * MN + i];
        if (accum) C[i] += v; else C[i] = v;
    }
}

// ---------------- causal depthwise conv (k=4) + bias + silu -----------------
__global__ __launch_bounds__(256) void conv_silu_kernel(const float* __restrict__ xz,
        const float* __restrict__ w, const float* __restrict__ cb,
        float* __restrict__ u) {
    int g = blockIdx.x * 256 + threadIdx.x;
    int d = g % D_INNER;
    int m = g / D_INNER;
    int l = m % SEQ;
    int b = m / SEQ;
    float acc = cb[d];
    #pragma unroll
    for (int j = 0; j < 4; ++j) {
        int ll = l - 3 + j;
        if (ll >= 0)
            acc += xz[(long)(b * SEQ + ll) * (2 * D_INNER) + d] * w[d * 4 + j];
    }
    u[(long)m * D_INNER + d] = siluf(acc);
}

// ---------------- selective scan + skip + z-gate (LDS-tiled) ----------------
#define SCAN_TILE 64
__global__ __launch_bounds__(256) void scan_kernel(const float* __restrict__ dt,
        const float* __restrict__ u, const float* __restrict__ dbc,
        const float* __restrict__ xz, const float* __restrict__ A_log,
        const float* __restrict__ Dskip, const float* __restrict__ h0,
        float* __restrict__ y, float* __restrict__ outstate) {
    __shared__ float sdt[SCAN_TILE][16];
    __shared__ float su [SCAN_TILE][16];
    __shared__ float sz [SCAN_TILE][16];
    __shared__ float sBC[SCAN_TILE][32];
    __shared__ float sy [SCAN_TILE][16];
    int t = threadIdx.x;
    int s = t & 15;
    int pair = t >> 4;                         // 0..15
    int gp = blockIdx.x * 16 + pair;
    int b = gp / D_INNER;                      // uniform per block
    int d = gp % D_INNER;
    int d0 = (blockIdx.x * 16) % D_INNER;      // block's base d
    float A_s = -__expf(A_log[d * D_STATE + s]);
    float hst = h0 ? h0[(size_t)(b * D_INNER + d) * D_STATE + s] : 0.0f;
    float Dv = Dskip[d];
    for (int l0 = 0; l0 < SEQ; l0 += SCAN_TILE) {
        #pragma unroll
        for (int k = 0; k < 4; ++k) {
            int idx = t + k * 256;
            int l = idx >> 4, j = idx & 15;
            size_t m = (size_t)(b * SEQ + l0 + l);
            sdt[l][j] = dt[m * D_INNER + d0 + j];
            su [l][j] = u [m * D_INNER + d0 + j];
            float zv  = xz[m * (2 * D_INNER) + D_INNER + d0 + j];
            sz [l][j] = siluf(zv);
        }
        #pragma unroll
        for (int k = 0; k < 8; ++k) {
            int idx = t + k * 256;
            int l = idx >> 5, c = idx & 31;
            size_t m = (size_t)(b * SEQ + l0 + l);
            sBC[l][c] = dbc[m * DBC_COLS + DT_RANK + c];
        }
        __syncthreads();
        #pragma unroll 4
        for (int l = 0; l < SCAN_TILE; ++l) {
            float dtv = sdt[l][pair];
            float uv  = su [l][pair];
            float Bv  = sBC[l][s];
            float Cv  = sBC[l][16 + s];
            float dA = __expf(dtv * A_s);
            hst = dA * hst + dtv * Bv * uv;
            float p = hst * Cv;
            p += __shfl_xor(p, 1);
            p += __shfl_xor(p, 2);
            p += __shfl_xor(p, 4);
            p += __shfl_xor(p, 8);
            if (s == 0) sy[l][pair] = (p + Dv * uv) * sz[l][pair];
        }
        __syncthreads();
        #pragma unroll
        for (int k = 0; k < 4; ++k) {
            int idx = t + k * 256;
            int l = idx >> 4, j = idx & 15;
            size_t m = (size_t)(b * SEQ + l0 + l);
            y[m * D_INNER + d0 + j] = sy[l][j];
        }
    }
    if (outstate) outstate[(size_t)(b * D_INNER + d) * D_STATE + s] = hst;
}

// ---------------- h += time_embeds[timesteps[b], :] -------------------------
__global__ __launch_bounds__(256) void add_time_kernel(float* __restrict__ h,
        const float* __restrict__ te, const int* __restrict__ ts) {
    int g = blockIdx.x * 256 + threadIdx.x;
    int m = g / D_MODEL;
    int k = g - m * D_MODEL;
    int b = m / SEQ;
    h[g] += te[(long)ts[b] * D_MODEL + k];
}

extern "C" void kernel_launch(void* const* d_in, const int* in_sizes, int n_in,
                              void* d_out, int out_size, void* d_ws, size_t ws_size,
                              hipStream_t stream) {
    const float* states     = (const float*)d_in[0];
    const int*   timesteps  = (const int*)d_in[1];
    const int*   input_ids  = (const int*)d_in[2];
    const float* time_emb   = (const float*)d_in[3];
    const float* embed      = (const float*)d_in[4];
    const float* norm_w     = (const float*)d_in[5];
    const float* in_proj_w  = (const float*)d_in[6];
    const float* conv_w     = (const float*)d_in[7];
    const float* conv_b     = (const float*)d_in[8];
    const float* x_proj_w   = (const float*)d_in[9];
    const float* dt_proj_w  = (const float*)d_in[10];
    const float* dt_proj_b  = (const float*)d_in[11];
    const float* A_log      = (const float*)d_in[12];
    const float* D_skip     = (const float*)d_in[13];
    const float* out_proj_w = (const float*)d_in[14];
    float* out = (float*)d_out;

    // workspace carve-up (fp32)
    float* h   = (float*)d_ws;                  // 393216
    float* x   = h   + M_ROWS * D_MODEL;        // 393216
    float* xz  = x   + M_ROWS * D_MODEL;        // 1572864
    float* u   = xz  + M_ROWS * 2 * D_INNER;    // 786432
    float* dbc = u   + M_ROWS * D_INNER;        // 40960
    float* dt  = dbc + M_ROWS * DBC_COLS;       // 786432
    float* y   = dt  + M_ROWS * D_INNER;        // 786432
    // aliased split-K partial buffers (lifetimes verified):
    float* px  = x;   // 4*512*80 = 163840 <= 393216; x dead after in_proj GEMM
    float* po  = u;   // 4*512*768 = 1572864 <= u+dbc+dt span (1613824); dead after scan

    gather_kernel<<<M_ROWS, 256, 0, stream>>>(input_ids, embed, h);

    for (int l = 0; l < NLAYERS; ++l) {
        const float* nw  = norm_w     + (size_t)l * D_MODEL;
        const float* iw  = in_proj_w  + (size_t)l * 2 * D_INNER * D_MODEL;
        const float* cw  = conv_w     + (size_t)l * D_INNER * 4;
        const float* cb  = conv_b     + (size_t)l * D_INNER;
        const float* xw  = x_proj_w   + (size_t)l * DBC_COLS * D_INNER;
        const float* dw  = dt_proj_w  + (size_t)l * D_INNER * DT_RANK;
        const float* db  = dt_proj_b  + (size_t)l * D_INNER;
        const float* al  = A_log      + (size_t)l * D_INNER * D_STATE;
        const float* dsk = D_skip     + (size_t)l * D_INNER;
        const float* ow  = out_proj_w + (size_t)l * D_MODEL * D_INNER;

        rmsnorm_kernel<<<M_ROWS, 256, 0, stream>>>(h, nw, x);

        // xz[512,3072] = x[512,768] @ in_w^T
        gemm_nt_mfma<<<dim3(2 * D_INNER / 64, M_ROWS / 64, 1), 256, 0, stream>>>(
            x, iw, xz, M_ROWS, 2 * D_INNER, D_MODEL, D_MODEL, D_MODEL, nullptr, 0, D_MODEL);

        conv_silu_kernel<<<M_ROWS * D_INNER / 256, 256, 0, stream>>>(xz, cw, cb, u);

        // dbc[512,80] = u[512,1536] @ x_w^T   (split-K x4)
        gemm_nt_mfma<<<dim3(2, M_ROWS / 64, 4), 256, 0, stream>>>(
            u, xw, px, M_ROWS, DBC_COLS, D_INNER, D_INNER, D_INNER, nullptr, 0, D_INNER / 4);
        reduce_splitk<<<(M_ROWS * DBC_COLS + 255) / 256, 256, 0, stream>>>(
            px, dbc, M_ROWS * DBC_COLS, 0);

        // dt[512,1536] = softplus(dbc[:, :48] @ dt_w^T + dt_b)
        gemm_nt_mfma<<<dim3(D_INNER / 64, M_ROWS / 64, 1), 256, 0, stream>>>(
            dbc, dw, dt, M_ROWS, D_INNER, DT_RANK, DBC_COLS, DT_RANK, db, 1, DT_RANK);

        const float* h0  = (l >= 21) ? states + (size_t)(l - 21) * BATCH * D_INNER * D_STATE : nullptr;
        float* ostate    = (l >= 21) ? out + (size_t)(l - 21) * BATCH * D_INNER * D_STATE : nullptr;
        scan_kernel<<<BATCH * D_INNER / 16, 256, 0, stream>>>(
            dt, u, dbc, xz, al, dsk, h0, y, ostate);

        // h[512,768] += y[512,1536] @ out_w^T   (split-K x4)
        gemm_nt_mfma<<<dim3(D_MODEL / 64, M_ROWS / 64, 4), 256, 0, stream>>>(
            y, ow, po, M_ROWS, D_MODEL, D_INNER, D_INNER, D_INNER, nullptr, 0, D_INNER / 4);
        reduce_splitk<<<(M_ROWS * D_MODEL + 255) / 256, 256, 0, stream>>>(
            po, h, M_ROWS * D_MODEL, 1);

        if (l == 20) {
            add_time_kernel<<<M_ROWS * D_MODEL / 256, 256, 0, stream>>>(h, time_emb, timesteps);
        }
    }
}

// Round 2
// 4140.803 us; speedup vs baseline: 1.2849x; 1.0885x over previous
//
#include <hip/hip_runtime.h>
#include <math.h>

#define D_MODEL 768
#define D_INNER 1536
#define D_STATE 16
#define DT_RANK 48
#define NLAYERS 24
#define BATCH 2
#define SEQ 256
#define M_ROWS (BATCH*SEQ)   // 512
#define DBC_COLS (DT_RANK + 2*D_STATE)  // 80

typedef __bf16 bf16x8 __attribute__((ext_vector_type(8)));
typedef float f32x4 __attribute__((ext_vector_type(4)));
typedef unsigned int u32;
#define AS1 __attribute__((address_space(1)))
#define AS3 __attribute__((address_space(3)))

__device__ __forceinline__ float siluf(float x) {
    return x / (1.0f + __expf(-x));
}
__device__ __forceinline__ void split1(float v, __bf16* hp, __bf16* lp) {
    __bf16 hb = (__bf16)v;
    *hp = hb;
    *lp = (__bf16)(v - (float)hb);
}

// ---------------- embedding gather ------------------------------------------
__global__ __launch_bounds__(256) void gather_kernel(const int* __restrict__ ids,
        const float* __restrict__ embed, float* __restrict__ h) {
    int m = blockIdx.x;
    long id = ids[m];
    const float* src = embed + id * D_MODEL;
    float* dst = h + m * D_MODEL;
    for (int k = threadIdx.x; k < D_MODEL; k += 256) dst[k] = src[k];
}

// ---------------- weight splitting (once per call) --------------------------
// straight split of n8*8 contiguous f32 -> bf16 hi/lo
__global__ __launch_bounds__(256) void split8_kernel(const float* __restrict__ src,
        __bf16* __restrict__ hi, __bf16* __restrict__ lo, long n8) {
    long i = (long)blockIdx.x * 256 + threadIdx.x;
    if (i >= n8) return;
    const float4* s = (const float4*)(src + i * 8);
    float4 p = s[0], q = s[1];
    float v[8] = {p.x, p.y, p.z, p.w, q.x, q.y, q.z, q.w};
    bf16x8 hv, lv;
    #pragma unroll
    for (int j = 0; j < 8; ++j) {
        __bf16 hb = (__bf16)v[j];
        hv[j] = hb;
        lv[j] = (__bf16)(v[j] - (float)hb);
    }
    *(bf16x8*)(hi + i * 8) = hv;
    *(bf16x8*)(lo + i * 8) = lv;
}

// x_proj weights: [24][80][1536] -> padded [24][128][1536] hi/lo (pad rows zero)
__global__ __launch_bounds__(256) void padsplit_x(const float* __restrict__ src,
        __bf16* __restrict__ hi, __bf16* __restrict__ lo) {
    long i = (long)blockIdx.x * 256 + threadIdx.x;
    if (i >= 24L * 128 * 1536) return;
    long c = i % 1536;
    long rl = i / 1536;
    int row = (int)(rl % 128);
    int l = (int)(rl / 128);
    float v = (row < DBC_COLS) ? src[((long)l * DBC_COLS + row) * 1536 + c] : 0.f;
    split1(v, hi + i, lo + i);
}

// dt_proj weights: [24][1536][48] -> padded [24][1536][64] hi/lo (pad cols zero)
__global__ __launch_bounds__(256) void padsplit_dt(const float* __restrict__ src,
        __bf16* __restrict__ hi, __bf16* __restrict__ lo) {
    long i = (long)blockIdx.x * 256 + threadIdx.x;
    if (i >= 24L * 1536 * 64) return;
    int c = (int)(i % 64);
    long r = (i / 64) % 1536;
    int l = (int)(i / (64L * 1536));
    float v = (c < DT_RANK) ? src[((long)l * 1536 + r) * DT_RANK + c] : 0.f;
    split1(v, hi + i, lo + i);
}

// ---------------- RMS norm -> bf16 hi/lo ------------------------------------
__global__ __launch_bounds__(256) void rmsnorm_kernel(const float* __restrict__ h,
        const float* __restrict__ w, __bf16* __restrict__ xh, __bf16* __restrict__ xl) {
    int m = blockIdx.x;
    const float* row = h + m * D_MODEL;
    float v[3];
    float ss = 0.f;
    #pragma unroll
    for (int i = 0; i < 3; ++i) {
        v[i] = row[threadIdx.x + i * 256];
        ss += v[i] * v[i];
    }
    #pragma unroll
    for (int off = 32; off > 0; off >>= 1) ss += __shfl_down(ss, off);
    __shared__ float wsum[4];
    int lane = threadIdx.x & 63, wid = threadIdx.x >> 6;
    if (lane == 0) wsum[wid] = ss;
    __syncthreads();
    float tot = wsum[0] + wsum[1] + wsum[2] + wsum[3];
    float inv = rsqrtf(tot / (float)D_MODEL + 1e-5f);
    #pragma unroll
    for (int i = 0; i < 3; ++i) {
        int k = threadIdx.x + i * 256;
        float o = v[i] * inv * w[k];
        split1(o, xh + m * D_MODEL + k, xl + m * D_MODEL + k);
    }
}

// ---------------- NT GEMM, bf16 hi/lo operands, 3-term, gl_lds + dbuf -------
// C[M,N] (+)= (Ah+Al)[M,K] * (Bh+Bl)[N,K]^T, 3-term split product.
// Block tile 64x128, K-step 32, 4 waves each 32x64.
// LDS linear dest (global_load_lds); source pre-swizzled: cg_src = (l&3)^((l>>3)&3);
// read swizzle: 16B-slot col = lg ^ ((lr>>1)&3)  -> conflict-free.
#define LDSBUF 24576
__global__ __launch_bounds__(256) void gemm_bf16s(
        const __bf16* __restrict__ Ah, const __bf16* __restrict__ Al, int lda,
        const __bf16* __restrict__ Bh, const __bf16* __restrict__ Bl, int ldb,
        float* __restrict__ C, int M, int N,
        const float* __restrict__ bias, int epi, int kchunk) {
    __shared__ __align__(16) __bf16 smem[2 * LDSBUF / 2];
    const int t = threadIdx.x;
    const int lane = t & 63, w = t >> 6;
    const int m0 = blockIdx.y * 64, n0 = blockIdx.x * 128;
    const int kbeg = blockIdx.z * kchunk;
    // compute role
    const int wm = (w & 1) * 32, wn = (w >> 1) * 64;
    const int lr = lane & 15, lg = lane >> 4;
    const int swz = ((lg ^ ((lr >> 1) & 3)) << 4);   // byte offset within 64B row
    // staging role: 24 wave-loads of 1KB per k-step; this wave owns ids w*6..w*6+5
    const int srow = lane >> 2;                       // row within 16-row group
    const int scg = (lane & 3) ^ ((lane >> 3) & 3);   // pre-swizzled source colgroup
    const __bf16* gsrc[6];
    int loff[6];
    #pragma unroll
    for (int i = 0; i < 6; ++i) {
        int id = w * 6 + i;
        int arr = (id < 4) ? 0 : (id < 8) ? 1 : (id < 16) ? 2 : 3;
        int rowbase = (arr < 2) ? ((id & 3) << 4) : ((id & 7) << 4);
        const __bf16* base;
        int ld, r0, arroff;
        if (arr == 0)      { base = Ah; ld = lda; r0 = m0; arroff = 0; }
        else if (arr == 1) { base = Al; ld = lda; r0 = m0; arroff = 4096; }
        else if (arr == 2) { base = Bh; ld = ldb; r0 = n0; arroff = 8192; }
        else               { base = Bl; ld = ldb; r0 = n0; arroff = 16384; }
        gsrc[i] = base + (size_t)(r0 + rowbase + srow) * ld + kbeg + scg * 8;
        loff[i] = arroff + rowbase * 64;
    }
    f32x4 acc[2][4] = {};
    const int nsteps = kchunk / 32;

    // prologue stage
    #pragma unroll
    for (int i = 0; i < 6; ++i) {
        __builtin_amdgcn_global_load_lds(
            (const AS1 u32*)(const void*)gsrc[i],
            (AS3 u32*)(void*)((char*)smem + loff[i]), 16, 0, 0);
    }
    __syncthreads();
    int cur = 0;
    for (int s = 0; s < nsteps; ++s) {
        if (s + 1 < nsteps) {
            int koff = (s + 1) * 32;
            int bufoff = (cur ^ 1) * LDSBUF;
            #pragma unroll
            for (int i = 0; i < 6; ++i) {
                __builtin_amdgcn_global_load_lds(
                    (const AS1 u32*)(const void*)(gsrc[i] + koff),
                    (AS3 u32*)(void*)((char*)smem + bufoff + loff[i]), 16, 0, 0);
            }
        }
        const char* sb = (const char*)smem + cur * LDSBUF;
        bf16x8 ah[2], al[2], bh[4], bl[4];
        #pragma unroll
        for (int mi = 0; mi < 2; ++mi) {
            int r = wm + mi * 16 + lr;
            ah[mi] = *(const bf16x8*)(sb + r * 64 + swz);
            al[mi] = *(const bf16x8*)(sb + 4096 + r * 64 + swz);
        }
        #pragma unroll
        for (int ni = 0; ni < 4; ++ni) {
            int r = wn + ni * 16 + lr;
            bh[ni] = *(const bf16x8*)(sb + 8192 + r * 64 + swz);
            bl[ni] = *(const bf16x8*)(sb + 16384 + r * 64 + swz);
        }
        #pragma unroll
        for (int mi = 0; mi < 2; ++mi) {
            #pragma unroll
            for (int ni = 0; ni < 4; ++ni) {
                acc[mi][ni] = __builtin_amdgcn_mfma_f32_16x16x32_bf16(ah[mi], bh[ni], acc[mi][ni], 0, 0, 0);
                acc[mi][ni] = __builtin_amdgcn_mfma_f32_16x16x32_bf16(ah[mi], bl[ni], acc[mi][ni], 0, 0, 0);
                acc[mi][ni] = __builtin_amdgcn_mfma_f32_16x16x32_bf16(al[mi], bh[ni], acc[mi][ni], 0, 0, 0);
            }
        }
        __syncthreads();
        cur ^= 1;
    }
    // epilogue: C/D layout col=lane&15, row=(lane>>4)*4+reg
    float* Cz = C + (size_t)blockIdx.z * M * N;
    #pragma unroll
    for (int ni = 0; ni < 4; ++ni) {
        int n = n0 + wn + ni * 16 + lr;
        if (n < N) {
            float bv = (epi == 1) ? bias[n] : 0.f;
            #pragma unroll
            for (int mi = 0; mi < 2; ++mi) {
                #pragma unroll
                for (int r = 0; r < 4; ++r) {
                    int m = m0 + wm + mi * 16 + lg * 4 + r;
                    float vv = acc[mi][ni][r];
                    if (epi == 1) {
                        vv += bv;
                        vv = vv > 20.f ? vv : log1pf(expf(vv));
                    }
                    Cz[(size_t)m * N + n] = vv;
                }
            }
        }
    }
}

// ---------------- reduce Z split-K partials ---------------------------------
__global__ __launch_bounds__(256) void reduce_splitk(const float* __restrict__ P,
        float* __restrict__ C, int MN, int Z, int accum) {
    int i = blockIdx.x * 256 + threadIdx.x;
    if (i < MN) {
        float v = 0.f;
        for (int z = 0; z < Z; ++z) v += P[(size_t)z * MN + i];
        if (accum) C[i] += v; else C[i] = v;
    }
}

// ---------------- reduce 8 partials of dbc + emit padded hi/lo --------------
__global__ __launch_bounds__(256) void reduce_dbc(const float* __restrict__ P,
        float* __restrict__ dbc, __bf16* __restrict__ dh, __bf16* __restrict__ dl) {
    int i = blockIdx.x * 256 + threadIdx.x;
    const int MN = M_ROWS * DBC_COLS;
    if (i >= MN) return;
    float v = 0.f;
    #pragma unroll
    for (int z = 0; z < 8; ++z) v += P[(size_t)z * MN + i];
    dbc[i] = v;
    int m = i / DBC_COLS, c = i - m * DBC_COLS;
    if (c < 64) {
        float vv = (c < DT_RANK) ? v : 0.f;
        split1(vv, dh + m * 64 + c, dl + m * 64 + c);
    }
}

// ---------------- causal depthwise conv (k=4) + bias + silu -----------------
__global__ __launch_bounds__(256) void conv_silu_kernel(const float* __restrict__ xz,
        const float* __restrict__ w, const float* __restrict__ cb,
        float* __restrict__ u, __bf16* __restrict__ uh, __bf16* __restrict__ ul) {
    int g = blockIdx.x * 256 + threadIdx.x;
    int d = g % D_INNER;
    int m = g / D_INNER;
    int l = m % SEQ;
    int b = m / SEQ;
    float acc = cb[d];
    #pragma unroll
    for (int j = 0; j < 4; ++j) {
        int ll = l - 3 + j;
        if (ll >= 0)
            acc += xz[(long)(b * SEQ + ll) * (2 * D_INNER) + d] * w[d * 4 + j];
    }
    float uv = siluf(acc);
    long o = (long)m * D_INNER + d;
    u[o] = uv;
    split1(uv, uh + o, ul + o);
}

// ---------------- selective scan + skip + z-gate (LDS-tiled) ----------------
#define SCAN_TILE 64
__global__ __launch_bounds__(256) void scan_kernel(const float* __restrict__ dt,
        const float* __restrict__ u, const float* __restrict__ dbc,
        const float* __restrict__ xz, const float* __restrict__ A_log,
        const float* __restrict__ Dskip, const float* __restrict__ h0,
        __bf16* __restrict__ yh, __bf16* __restrict__ yl,
        float* __restrict__ outstate) {
    __shared__ float sdt[SCAN_TILE][16];
    __shared__ float su [SCAN_TILE][16];
    __shared__ float sz [SCAN_TILE][16];
    __shared__ float sBC[SCAN_TILE][32];
    __shared__ float sy [SCAN_TILE][16];
    int t = threadIdx.x;
    int s = t & 15;
    int pair = t >> 4;
    int gp = blockIdx.x * 16 + pair;
    int b = gp / D_INNER;
    int d = gp % D_INNER;
    int d0 = (blockIdx.x * 16) % D_INNER;
    float A_s = -__expf(A_log[d * D_STATE + s]);
    float hst = h0 ? h0[(size_t)(b * D_INNER + d) * D_STATE + s] : 0.0f;
    float Dv = Dskip[d];
    for (int l0 = 0; l0 < SEQ; l0 += SCAN_TILE) {
        #pragma unroll
        for (int k = 0; k < 4; ++k) {
            int idx = t + k * 256;
            int l = idx >> 4, j = idx & 15;
            size_t m = (size_t)(b * SEQ + l0 + l);
            sdt[l][j] = dt[m * D_INNER + d0 + j];
            su [l][j] = u [m * D_INNER + d0 + j];
            float zv  = xz[m * (2 * D_INNER) + D_INNER + d0 + j];
            sz [l][j] = siluf(zv);
        }
        #pragma unroll
        for (int k = 0; k < 8; ++k) {
            int idx = t + k * 256;
            int l = idx >> 5, c = idx & 31;
            size_t m = (size_t)(b * SEQ + l0 + l);
            sBC[l][c] = dbc[m * DBC_COLS + DT_RANK + c];
        }
        __syncthreads();
        #pragma unroll 4
        for (int l = 0; l < SCAN_TILE; ++l) {
            float dtv = sdt[l][pair];
            float uv  = su [l][pair];
            float Bv  = sBC[l][s];
            float Cv  = sBC[l][16 + s];
            float dA = __expf(dtv * A_s);
            hst = dA * hst + dtv * Bv * uv;
            float p = hst * Cv;
            p += __shfl_xor(p, 1);
            p += __shfl_xor(p, 2);
            p += __shfl_xor(p, 4);
            p += __shfl_xor(p, 8);
            if (s == 0) sy[l][pair] = (p + Dv * uv) * sz[l][pair];
        }
        __syncthreads();
        #pragma unroll
        for (int k = 0; k < 4; ++k) {
            int idx = t + k * 256;
            int l = idx >> 4, j = idx & 15;
            size_t m = (size_t)(b * SEQ + l0 + l);
            split1(sy[l][j], yh + m * D_INNER + d0 + j, yl + m * D_INNER + d0 + j);
        }
    }
    if (outstate) outstate[(size_t)(b * D_INNER + d) * D_STATE + s] = hst;
}

// ---------------- h += time_embeds[timesteps[b], :] -------------------------
__global__ __launch_bounds__(256) void add_time_kernel(float* __restrict__ h,
        const float* __restrict__ te, const int* __restrict__ ts) {
    int g = blockIdx.x * 256 + threadIdx.x;
    int m = g / D_MODEL;
    int k = g - m * D_MODEL;
    int b = m / SEQ;
    h[g] += te[(long)ts[b] * D_MODEL + k];
}

extern "C" void kernel_launch(void* const* d_in, const int* in_sizes, int n_in,
                              void* d_out, int out_size, void* d_ws, size_t ws_size,
                              hipStream_t stream) {
    const float* states     = (const float*)d_in[0];
    const int*   timesteps  = (const int*)d_in[1];
    const int*   input_ids  = (const int*)d_in[2];
    const float* time_emb   = (const float*)d_in[3];
    const float* embed      = (const float*)d_in[4];
    const float* norm_w     = (const float*)d_in[5];
    const float* in_proj_w  = (const float*)d_in[6];
    const float* conv_w     = (const float*)d_in[7];
    const float* conv_b     = (const float*)d_in[8];
    const float* x_proj_w   = (const float*)d_in[9];
    const float* dt_proj_w  = (const float*)d_in[10];
    const float* dt_proj_b  = (const float*)d_in[11];
    const float* A_log      = (const float*)d_in[12];
    const float* D_skip     = (const float*)d_in[13];
    const float* out_proj_w = (const float*)d_in[14];
    float* out = (float*)d_out;

    // ---- workspace carve-up ----
    float* h    = (float*)d_ws;                 // 512*768
    float* xz   = h    + M_ROWS * D_MODEL;      // 512*3072
    float* u    = xz   + M_ROWS * 2 * D_INNER;  // 512*1536
    float* dbcf = u    + M_ROWS * D_INNER;      // 512*80
    float* dtf  = dbcf + M_ROWS * DBC_COLS;     // 512*1536
    float* px   = dtf  + M_ROWS * D_INNER;      // 8*512*80
    float* po   = px   + 8 * M_ROWS * DBC_COLS; // 4*512*768
    __bf16* bp  = (__bf16*)(po + 4 * M_ROWS * D_MODEL);
    __bf16* xh = bp;               bp += M_ROWS * D_MODEL;
    __bf16* xl = bp;               bp += M_ROWS * D_MODEL;
    __bf16* uh = bp;               bp += M_ROWS * D_INNER;
    __bf16* ul = bp;               bp += M_ROWS * D_INNER;
    __bf16* yh = bp;               bp += M_ROWS * D_INNER;
    __bf16* yl = bp;               bp += M_ROWS * D_INNER;
    __bf16* dbh = bp;              bp += M_ROWS * 64;
    __bf16* dbl_ = bp;             bp += M_ROWS * 64;
    const long IN_W = 24L * 2 * D_INNER * D_MODEL;   // 56623104
    const long OUT_W = 24L * D_MODEL * D_INNER;      // 28311552
    const long X_W  = 24L * 128 * D_INNER;           // 4718592 (padded)
    const long DT_W = 24L * D_INNER * 64;            // 2359296 (padded)
    __bf16* wih = bp;              bp += IN_W;
    __bf16* wil = bp;              bp += IN_W;
    __bf16* woh = bp;              bp += OUT_W;
    __bf16* wol = bp;              bp += OUT_W;
    __bf16* wxh = bp;              bp += X_W;
    __bf16* wxl = bp;              bp += X_W;
    __bf16* wdh = bp;              bp += DT_W;
    __bf16* wdl = bp;              bp += DT_W;

    gather_kernel<<<M_ROWS, 256, 0, stream>>>(input_ids, embed, h);

    // ---- weight split pre-pass ----
    split8_kernel<<<(int)(IN_W / 8 / 256), 256, 0, stream>>>(in_proj_w, wih, wil, IN_W / 8);
    split8_kernel<<<(int)(OUT_W / 8 / 256), 256, 0, stream>>>(out_proj_w, woh, wol, OUT_W / 8);
    padsplit_x<<<(int)(X_W / 256), 256, 0, stream>>>(x_proj_w, wxh, wxl);
    padsplit_dt<<<(int)(DT_W / 256), 256, 0, stream>>>(dt_proj_w, wdh, wdl);

    for (int l = 0; l < NLAYERS; ++l) {
        const float* nw  = norm_w    + (size_t)l * D_MODEL;
        const float* cw  = conv_w    + (size_t)l * D_INNER * 4;
        const float* cb  = conv_b    + (size_t)l * D_INNER;
        const float* db  = dt_proj_b + (size_t)l * D_INNER;
        const float* al  = A_log     + (size_t)l * D_INNER * D_STATE;
        const float* dsk = D_skip    + (size_t)l * D_INNER;
        const __bf16* lwih = wih + (size_t)l * 2 * D_INNER * D_MODEL;
        const __bf16* lwil = wil + (size_t)l * 2 * D_INNER * D_MODEL;
        const __bf16* lwoh = woh + (size_t)l * D_MODEL * D_INNER;
        const __bf16* lwol = wol + (size_t)l * D_MODEL * D_INNER;
        const __bf16* lwxh = wxh + (size_t)l * 128 * D_INNER;
        const __bf16* lwxl = wxl + (size_t)l * 128 * D_INNER;
        const __bf16* lwdh = wdh + (size_t)l * D_INNER * 64;
        const __bf16* lwdl = wdl + (size_t)l * D_INNER * 64;

        rmsnorm_kernel<<<M_ROWS, 256, 0, stream>>>(h, nw, xh, xl);

        // xz[512,3072] = x @ in_w^T
        gemm_bf16s<<<dim3(2 * D_INNER / 128, M_ROWS / 64, 1), 256, 0, stream>>>(
            xh, xl, D_MODEL, lwih, lwil, D_MODEL, xz, M_ROWS, 2 * D_INNER,
            nullptr, 0, D_MODEL);

        conv_silu_kernel<<<M_ROWS * D_INNER / 256, 256, 0, stream>>>(xz, cw, cb, u, uh, ul);

        // dbc partials: px[z][512][80] = u @ x_w^T (split-K x8)
        gemm_bf16s<<<dim3(1, M_ROWS / 64, 8), 256, 0, stream>>>(
            uh, ul, D_INNER, lwxh, lwxl, D_INNER, px, M_ROWS, DBC_COLS,
            nullptr, 0, D_INNER / 8);
        reduce_dbc<<<(M_ROWS * DBC_COLS + 255) / 256, 256, 0, stream>>>(px, dbcf, dbh, dbl_);

        // dt[512,1536] = softplus(dbc[:, :48] @ dt_w^T + dt_b)   (K padded to 64)
        gemm_bf16s<<<dim3(D_INNER / 128, M_ROWS / 64, 1), 256, 0, stream>>>(
            dbh, dbl_, 64, lwdh, lwdl, 64, dtf, M_ROWS, D_INNER, db, 1, 64);

        const float* h0  = (l >= 21) ? states + (size_t)(l - 21) * BATCH * D_INNER * D_STATE : nullptr;
        float* ostate    = (l >= 21) ? out + (size_t)(l - 21) * BATCH * D_INNER * D_STATE : nullptr;
        scan_kernel<<<BATCH * D_INNER / 16, 256, 0, stream>>>(
            dtf, u, dbcf, xz, al, dsk, h0, yh, yl, ostate);

        // h += y @ out_w^T (split-K x4)
        gemm_bf16s<<<dim3(D_MODEL / 128, M_ROWS / 64, 4), 256, 0, stream>>>(
            yh, yl, D_INNER, lwoh, lwol, D_INNER, po, M_ROWS, D_MODEL,
            nullptr, 0, D_INNER / 4);
        reduce_splitk<<<(M_ROWS * D_MODEL + 255) / 256, 256, 0, stream>>>(
            po, h, M_ROWS * D_MODEL, 4, 1);

        if (l == 20) {
            add_time_kernel<<<M_ROWS * D_MODEL / 256, 256, 0, stream>>>(h, time_emb, timesteps);
        }
    }
}